// Round 1
// baseline (476.839 us; speedup 1.0000x reference)
//
#include <hip/hip_runtime.h>
#include <hip/hip_fp16.h>
#include <math.h>

namespace {
constexpr int S = 192;
constexpr long long S2 = (long long)S * S;
constexpr long long S3 = (long long)S * S2;
constexpr int NB = 4;
constexpr int K = 11;
constexpr int R = 5;
constexpr int HCH = 32;   // A: h-outputs per block (6 chunks)
constexpr int DCH = 48;   // B: d-outputs per block (4 chunks)
constexpr float C1f = 1e-4f;
constexpr float C2f = 9e-4f;

struct GaussW { float g[K]; };

__global__ void k_init(double* acc) { *acc = 0.0; }

__global__ void k_final(const double* __restrict__ acc, float* __restrict__ out) {
  out[0] = (float)(acc[0] / (double)(NB * S3));
}

// ======================= Kernel A =======================
// Fused W+H blur. Fields 0..3 (mux,muy,bxx,byy) packed as 4xfp16 in uint2;
// field 4 (bxy) separate fp16.
// R7: T14 async-STAGE split — issue next batch's global loads into registers
// BEFORE consuming the current batch (HBM latency hides under ~2900 cycles
// of consume FMA), ds_write them only after the post-consume barrier.
// la/lb are fully unrolled, compile-time indexed (22 VGPRs, no scratch).

template <int NROWS, bool GUARD>
__device__ __forceinline__ void loadA(const float* pg, const float* pp, int r0,
                                      int w, float (&la)[K], float (&lb)[K]) {
#pragma unroll
  for (int j = 0; j < NROWS; ++j) {
    int r = r0 + j;
    bool ok = !GUARD || ((unsigned)r < (unsigned)S);
    la[j] = ok ? pg[(long long)r * S + w] : 0.f;
    lb[j] = ok ? pp[(long long)r * S + w] : 0.f;
  }
}

template <int NROWS>
__device__ __forceinline__ void writeA(const float (&la)[K], const float (&lb)[K],
                                       int w, float2 (*rb)[208]) {
#pragma unroll
  for (int j = 0; j < NROWS; ++j) rb[j][8 + w] = make_float2(la[j], lb[j]);
}

template <int NROWS, bool EMITALL>
__device__ __forceinline__ void consumeA(
    const float2 (*rb)[208], int w, const GaussW& Wt,
    float2 (&w01)[K], float2 (&w23)[K], float (&w4v)[K],
    uint2* p0123, __half* p4, long long obase, int hbase) {
#pragma unroll
  for (int j = 0; j < NROWS; ++j) {
    // W-blur the 5 products for staged row j
    float2 s01 = make_float2(0.f, 0.f), s23 = make_float2(0.f, 0.f);
    float s4 = 0.f;
#pragma unroll
    for (int i = 0; i < K; ++i) {
      float2 ab = rb[j][w + 3 + i];
      float g = Wt.g[i];
      s01.x = fmaf(g, ab.x, s01.x);
      s01.y = fmaf(g, ab.y, s01.y);
      float ta = g * ab.x, tb = g * ab.y;
      s23.x = fmaf(ta, ab.x, s23.x);
      s23.y = fmaf(tb, ab.y, s23.y);
      s4 = fmaf(ta, ab.y, s4);
    }
    w01[j] = s01; w23[j] = s23; w4v[j] = s4;  // ring slot = counter % 11 = j
    if (EMITALL || j == K - 1) {              // compile-time
      float2 m01 = make_float2(0.f, 0.f), m23 = make_float2(0.f, 0.f);
      float m4 = 0.f;
#pragma unroll
      for (int i = 0; i < K; ++i) {
        const int sl = (j + 1 + i) % K;       // compile-time
        float g = Wt.g[i];
        m01.x = fmaf(g, w01[sl].x, m01.x);
        m01.y = fmaf(g, w01[sl].y, m01.y);
        m23.x = fmaf(g, w23[sl].x, m23.x);
        m23.y = fmaf(g, w23[sl].y, m23.y);
        m4 = fmaf(g, w4v[sl], m4);
      }
      long long o = obase + (long long)(hbase + j) * S;
      __half2 h01 = __floats2half2_rn(m01.x, m01.y);
      __half2 h23 = __floats2half2_rn(m23.x, m23.y);
      uint2 v;
      v.x = __builtin_bit_cast(unsigned, h01);
      v.y = __builtin_bit_cast(unsigned, h23);
      p0123[o] = v;
      p4[o] = __float2half(m4);
    }
  }
}

// grid = (dz=S, hchunk=6, n); block = 192 (w). Batches of 11,11,11,9 rows;
// single 18.4 KB LDS buffer, 2 barriers per batch, register prefetch one
// batch ahead (loads in flight across the consume phase).
// Row ranges: b0 = h0-5..h0+5 (GUARD: neg), b1 <= 176, b2 <= 187 (safe),
// b3 = h0+28..h0+36 <= 196 (GUARD).
__global__ __launch_bounds__(192) void k_blurWH(
    const float* __restrict__ gt, const float* __restrict__ pr,
    uint2* __restrict__ p0123, __half* __restrict__ p4,
    long long in_base, GaussW Wt) {
  __shared__ float2 rowbuf[K][208];  // [8..199] data, [0..7]/[200..207] pads
  const int w = threadIdx.x;
  const int dz = blockIdx.x;
  const int h0 = (int)blockIdx.y * HCH;
  const long long n = blockIdx.z;
  const float* pg = gt + in_base + (n * S + dz) * S2;
  const float* pp = pr + in_base + (n * S + dz) * S2;
  const long long obase = (n * S + dz) * S2 + w;

  if (w < 176) {  // zero halo pads once (before first barrier)
    int j = w >> 4, q = w & 15;
    rowbuf[j][(q < 8) ? q : (192 + q)] = make_float2(0.f, 0.f);
  }

  float2 w01[K], w23[K];
  float w4v[K];  // no init needed: batch0 writes all 11 slots before 1st emit
  float la[K], lb[K];

  // batch 0 (prologue: no overlap possible)
  loadA<K, true>(pg, pp, h0 - R, w, la, lb);
  writeA<K>(la, lb, w, rowbuf);
  __syncthreads();
  loadA<K, false>(pg, pp, h0 + 6, w, la, lb);    // prefetch batch 1
  consumeA<K, false>(rowbuf, w, Wt, w01, w23, w4v, p0123, p4, obase, h0 - 10);
  __syncthreads();
  writeA<K>(la, lb, w, rowbuf);
  __syncthreads();
  loadA<K, false>(pg, pp, h0 + 17, w, la, lb);   // prefetch batch 2
  consumeA<K, true>(rowbuf, w, Wt, w01, w23, w4v, p0123, p4, obase, h0 + 1);
  __syncthreads();
  writeA<K>(la, lb, w, rowbuf);
  __syncthreads();
  loadA<9, true>(pg, pp, h0 + 28, w, la, lb);    // prefetch batch 3
  consumeA<K, true>(rowbuf, w, Wt, w01, w23, w4v, p0123, p4, obase, h0 + 12);
  __syncthreads();
  writeA<9>(la, lb, w, rowbuf);
  __syncthreads();
  consumeA<9, true>(rowbuf, w, Wt, w01, w23, w4v, p0123, p4, obase, h0 + 23);
}

// ======================= Kernel B =======================
// R7: ring kept PACKED fp16 (33 VGPRs instead of 55 f32) to drop total VGPR
// under the 128 halving boundary (occupancy tier 8->16 waves/CU). Conversion
// moved to tap time: fmaf(g, half2float(h), acc) — backend can fold to
// v_fma_mix_f32. Numerically identical to the f32-ring version (same fp16
// source bits, same f32 accumulation order).

template <int N, bool GUARD>
__device__ __forceinline__ void stageB(const uint2* q0123, const unsigned short* q4,
                                       int plane0, uint2 (&sab)[K],
                                       unsigned short (&se)[K]) {
#pragma unroll
  for (int j = 0; j < N; ++j) {
    int d = plane0 + j;
    bool ok = !GUARD || ((unsigned)d < (unsigned)S);
    long long o = (long long)d * S2;
    sab[j] = ok ? q0123[o] : make_uint2(0u, 0u);  // fp16 bits 0 == 0.0
    se[j] = ok ? q4[o] : (unsigned short)0;
  }
}

template <int NOUT>
__device__ __forceinline__ void consumeB(
    const uint2 (&sab)[K], const unsigned short (&se)[K],
    const GaussW& Wt, uint2 (&rab)[K], unsigned short (&re)[K],
    double& lsum) {
  float fsum = 0.f;
#pragma unroll
  for (int j = 0; j < NOUT; ++j) {
    const int sw = (10 + j) % K;              // compile-time commit slot
    rab[sw] = sab[j];
    re[sw] = se[j];
    float2 m01 = make_float2(0.f, 0.f), m23 = make_float2(0.f, 0.f);
    float m4 = 0.f;
#pragma unroll
    for (int i = 0; i < K; ++i) {
      const int sl = (j + i) % K;             // compile-time
      float g = Wt.g[i];
      float2 v01 = __half22float2(__builtin_bit_cast(__half2, rab[sl].x));
      float2 v23 = __half22float2(__builtin_bit_cast(__half2, rab[sl].y));
      float ve = __half2float(__builtin_bit_cast(__half, re[sl]));
      m01.x = fmaf(g, v01.x, m01.x);
      m01.y = fmaf(g, v01.y, m01.y);
      m23.x = fmaf(g, v23.x, m23.x);
      m23.y = fmaf(g, v23.y, m23.y);
      m4 = fmaf(g, ve, m4);
    }
    float mux = m01.x, muy = m01.y, bxx = m23.x, byy = m23.y, bxy = m4;
    float mux2 = mux * mux, muy2 = muy * muy, muxy = mux * muy;
    float sx = bxx - mux2, sy = byy - muy2, sxy = bxy - muxy;
    float num = fmaf(2.f, muxy, C1f) * fmaf(2.f, sxy, C2f);
    float den = (mux2 + muy2 + C1f) * (sx + sy + C2f);
    fsum += 1.f - num * __builtin_amdgcn_rcpf(den);
  }
  lsum += (double)fsum;
}

// D-blur + SSIM + mean-reduce. grid = (h=S, n, dchunk=4); block = 192 (w).
// Packed register ring of 11 planes, ping-pong staging one 11-batch ahead.
__global__ __launch_bounds__(192, 4) void k_blurD_ssim(
    const uint2* __restrict__ p0123, const __half* __restrict__ p4,
    double* __restrict__ acc, GaussW Wt) {
  const int w = threadIdx.x;
  const int h = blockIdx.x;
  const long long n = blockIdx.y;
  const int d0 = (int)blockIdx.z * DCH;
  const long long base = n * S3 + (long long)h * S + w;
  const uint2* q0123 = p0123 + base;
  const unsigned short* q4 = (const unsigned short*)(p4 + base);

  uint2 rab[K];
  unsigned short re[K];
  // preload counters 0..9 -> slots 0..9 (planes d0-5..d0+4, guard low)
#pragma unroll
  for (int c = 0; c < K - 1; ++c) {
    int d = d0 - R + c;
    bool ok = (unsigned)d < (unsigned)S;
    long long o = (long long)d * S2;
    rab[c] = ok ? q0123[o] : make_uint2(0u, 0u);
    re[c] = ok ? q4[o] : (unsigned short)0;
  }
  rab[K - 1] = make_uint2(0u, 0u);
  re[K - 1] = 0;

  uint2 sab0[K], sab1[K];
  unsigned short se0[K], se1[K];
  double lsum = 0.0;

  // plane ranges: d0+5..15, d0+16..26, d0+27..37 (max 181: safe);
  // d0+38..48 and d0+49..52 guarded (max 196).
  stageB<K, false>(q0123, q4, d0 + 5, sab0, se0);   // counters 10..20
  stageB<K, false>(q0123, q4, d0 + 16, sab1, se1);  // counters 21..31
  consumeB<K>(sab0, se0, Wt, rab, re, lsum);        // t = 0..10
  stageB<K, false>(q0123, q4, d0 + 27, sab0, se0);  // counters 32..42
  consumeB<K>(sab1, se1, Wt, rab, re, lsum);        // t = 11..21
  stageB<K, true>(q0123, q4, d0 + 38, sab1, se1);   // counters 43..53
  consumeB<K>(sab0, se0, Wt, rab, re, lsum);        // t = 22..32
  stageB<4, true>(q0123, q4, d0 + 49, sab0, se0);   // counters 54..57
  consumeB<K>(sab1, se1, Wt, rab, re, lsum);        // t = 33..43
  consumeB<4>(sab0, se0, Wt, rab, re, lsum);        // t = 44..47

  // block reduction: wave shuffle -> LDS -> one atomic per block
  double v = lsum;
#pragma unroll
  for (int o = 32; o > 0; o >>= 1) v += __shfl_down(v, o, 64);
  __shared__ double wsum[3];
  int lane = threadIdx.x & 63, wv = threadIdx.x >> 6;
  if (lane == 0) wsum[wv] = v;
  __syncthreads();
  if (threadIdx.x == 0) atomicAdd(acc, wsum[0] + wsum[1] + wsum[2]);
}

}  // namespace

extern "C" void kernel_launch(void* const* d_in, const int* in_sizes, int n_in,
                              void* d_out, int out_size, void* d_ws, size_t ws_size,
                              hipStream_t stream) {
  (void)in_sizes; (void)n_in; (void)out_size;
  const float* gt = (const float*)d_in[0];
  const float* pr = (const float*)d_in[1];
  float* out = (float*)d_out;
  double* acc = (double*)d_ws;

  GaussW W;
  {
    double gg[K], sum = 0.0;
    for (int i = 0; i < K; ++i) {
      double x = (double)(i - K / 2);
      gg[i] = exp(-(x * x) / (2.0 * 1.5 * 1.5)) / (sqrt(2.0 * M_PI) * 1.5);
      sum += gg[i];
    }
    for (int i = 0; i < K; ++i) W.g[i] = (float)(gg[i] / sum);
  }

  auto run = [&](long long base_n, int nb) {
    size_t vox = (size_t)nb * S3;
    uint2* p0123 = (uint2*)((char*)d_ws + 256);
    __half* p4 = (__half*)(p0123 + vox);
    k_blurWH<<<dim3(S, S / HCH, nb), dim3(192), 0, stream>>>(
        gt, pr, p0123, p4, base_n * S3, W);
    k_blurD_ssim<<<dim3(S, nb, S / DCH), dim3(192), 0, stream>>>(
        p0123, p4, acc, W);
  };
  auto need = [](int nb) { return (size_t)256 + (size_t)nb * S3 * 10; };  // 8+2 B/voxel

  k_init<<<dim3(1), dim3(1), 0, stream>>>(acc);
  if (ws_size >= need(4)) {
    run(0, 4);
  } else if (ws_size >= need(2)) {
    run(0, 2);
    run(2, 2);
  } else {
    for (int g = 0; g < NB; ++g) run(g, 1);
  }
  k_final<<<dim3(1), dim3(1), 0, stream>>>(acc, out);
}

// Round 2
// 426.164 us; speedup vs baseline: 1.1189x; 1.1189x over previous
//
#include <hip/hip_runtime.h>
#include <hip/hip_fp16.h>
#include <math.h>

namespace {
constexpr int S = 192;
constexpr long long S2 = (long long)S * S;
constexpr long long S3 = (long long)S * S2;
constexpr int NB = 4;
constexpr int K = 11;
constexpr int R = 5;
constexpr int HCH = 32;   // A: h-outputs per block (6 chunks)
constexpr int DCH = 48;   // B: d-outputs per block (4 chunks)
constexpr float C1f = 1e-4f;
constexpr float C2f = 9e-4f;

struct GaussW { float g[K]; };

__global__ void k_init(double* acc) { *acc = 0.0; }

__global__ void k_final(const double* __restrict__ acc, float* __restrict__ out) {
  out[0] = (float)(acc[0] / (double)(NB * S3));
}

// ======================= Kernel A =======================
// Fused W+H blur. Fields 0..3 (mux,muy,bxx,byy) packed as 4xfp16 in uint2;
// field 4 (bxy) separate fp16. R8: exact revert to the R6 structure (R7's
// register prefetch pushed VGPR 84->88, crossing the 512/84=6 -> 512/88=5
// waves/SIMD boundary: occupancy 30%->16%, dur +24us). Loads go straight
// to LDS within stageA; TLP hides the latency.

template <int NROWS, bool GUARD>
__device__ __forceinline__ void stageA(const float* pg, const float* pp, int r0,
                                       int w, float2 (*rb)[208]) {
  float la[NROWS], lb[NROWS];  // transient: dead before consume
#pragma unroll
  for (int j = 0; j < NROWS; ++j) {
    int r = r0 + j;
    bool ok = !GUARD || ((unsigned)r < (unsigned)S);
    la[j] = ok ? pg[(long long)r * S + w] : 0.f;
    lb[j] = ok ? pp[(long long)r * S + w] : 0.f;
  }
#pragma unroll
  for (int j = 0; j < NROWS; ++j) rb[j][8 + w] = make_float2(la[j], lb[j]);
}

template <int NROWS, bool EMITALL>
__device__ __forceinline__ void consumeA(
    const float2 (*rb)[208], int w, const GaussW& Wt,
    float2 (&w01)[K], float2 (&w23)[K], float (&w4v)[K],
    uint2* p0123, __half* p4, long long obase, int hbase) {
#pragma unroll
  for (int j = 0; j < NROWS; ++j) {
    // W-blur the 5 products for staged row j
    float2 s01 = make_float2(0.f, 0.f), s23 = make_float2(0.f, 0.f);
    float s4 = 0.f;
#pragma unroll
    for (int i = 0; i < K; ++i) {
      float2 ab = rb[j][w + 3 + i];
      float g = Wt.g[i];
      s01.x = fmaf(g, ab.x, s01.x);
      s01.y = fmaf(g, ab.y, s01.y);
      float ta = g * ab.x, tb = g * ab.y;
      s23.x = fmaf(ta, ab.x, s23.x);
      s23.y = fmaf(tb, ab.y, s23.y);
      s4 = fmaf(ta, ab.y, s4);
    }
    w01[j] = s01; w23[j] = s23; w4v[j] = s4;  // ring slot = counter % 11 = j
    if (EMITALL || j == K - 1) {              // compile-time
      float2 m01 = make_float2(0.f, 0.f), m23 = make_float2(0.f, 0.f);
      float m4 = 0.f;
#pragma unroll
      for (int i = 0; i < K; ++i) {
        const int sl = (j + 1 + i) % K;       // compile-time
        float g = Wt.g[i];
        m01.x = fmaf(g, w01[sl].x, m01.x);
        m01.y = fmaf(g, w01[sl].y, m01.y);
        m23.x = fmaf(g, w23[sl].x, m23.x);
        m23.y = fmaf(g, w23[sl].y, m23.y);
        m4 = fmaf(g, w4v[sl], m4);
      }
      long long o = obase + (long long)(hbase + j) * S;
      __half2 h01 = __floats2half2_rn(m01.x, m01.y);
      __half2 h23 = __floats2half2_rn(m23.x, m23.y);
      uint2 v;
      v.x = __builtin_bit_cast(unsigned, h01);
      v.y = __builtin_bit_cast(unsigned, h23);
      p0123[o] = v;
      p4[o] = __float2half(m4);
    }
  }
}

// grid = (dz=S, hchunk=6, n); block = 192 (w). Batches of 11,11,11,9 rows;
// single 18.4 KB LDS buffer (8 blocks/CU cap), 2 barriers per batch.
// Row ranges: b0 = h0-5..h0+5 (GUARD: neg), b1 <= 176, b2 <= 187 (safe),
// b3 = h0+28..h0+36 <= 196 (GUARD).
__global__ __launch_bounds__(192) void k_blurWH(
    const float* __restrict__ gt, const float* __restrict__ pr,
    uint2* __restrict__ p0123, __half* __restrict__ p4,
    long long in_base, GaussW Wt) {
  __shared__ float2 rowbuf[K][208];  // [8..199] data, [0..7]/[200..207] pads
  const int w = threadIdx.x;
  const int dz = blockIdx.x;
  const int h0 = (int)blockIdx.y * HCH;
  const long long n = blockIdx.z;
  const float* pg = gt + in_base + (n * S + dz) * S2;
  const float* pp = pr + in_base + (n * S + dz) * S2;
  const long long obase = (n * S + dz) * S2 + w;

  if (w < 176) {  // zero halo pads once (before first barrier)
    int j = w >> 4, q = w & 15;
    rowbuf[j][(q < 8) ? q : (192 + q)] = make_float2(0.f, 0.f);
  }

  float2 w01[K], w23[K];
  float w4v[K];  // no init needed: batch0 writes all 11 slots before 1st emit

  stageA<K, true>(pg, pp, h0 - R, w, rowbuf);
  __syncthreads();
  consumeA<K, false>(rowbuf, w, Wt, w01, w23, w4v, p0123, p4, obase, h0 - 10);
  __syncthreads();
  stageA<K, false>(pg, pp, h0 + 6, w, rowbuf);
  __syncthreads();
  consumeA<K, true>(rowbuf, w, Wt, w01, w23, w4v, p0123, p4, obase, h0 + 1);
  __syncthreads();
  stageA<K, false>(pg, pp, h0 + 17, w, rowbuf);
  __syncthreads();
  consumeA<K, true>(rowbuf, w, Wt, w01, w23, w4v, p0123, p4, obase, h0 + 12);
  __syncthreads();
  stageA<9, true>(pg, pp, h0 + 28, w, rowbuf);
  __syncthreads();
  consumeA<9, true>(rowbuf, w, Wt, w01, w23, w4v, p0123, p4, obase, h0 + 23);
}

// ======================= Kernel B =======================

template <int N, bool GUARD>
__device__ __forceinline__ void stageB(const uint2* q0123, const __half* q4,
                                       int plane0, uint2 (&sab)[K], __half (&se)[K]) {
#pragma unroll
  for (int j = 0; j < N; ++j) {
    int d = plane0 + j;
    bool ok = !GUARD || ((unsigned)d < (unsigned)S);
    long long o = (long long)d * S2;
    sab[j] = ok ? q0123[o] : make_uint2(0u, 0u);  // fp16 bits 0 == 0.0
    se[j] = ok ? q4[o] : __float2half(0.f);
  }
}

template <int NOUT>
__device__ __forceinline__ void consumeB(
    const uint2 (&sab)[K], const __half (&se)[K],
    const GaussW& Wt, float2 (&r01)[K], float2 (&r23)[K], float (&r4)[K],
    double& lsum) {
  float fsum = 0.f;
#pragma unroll
  for (int j = 0; j < NOUT; ++j) {
    const int sw = (10 + j) % K;              // compile-time commit slot
    r01[sw] = __half22float2(__builtin_bit_cast(__half2, sab[j].x));
    r23[sw] = __half22float2(__builtin_bit_cast(__half2, sab[j].y));
    r4[sw] = __half2float(se[j]);
    float2 m01 = make_float2(0.f, 0.f), m23 = make_float2(0.f, 0.f);
    float m4 = 0.f;
#pragma unroll
    for (int i = 0; i < K; ++i) {
      const int sl = (j + i) % K;             // compile-time
      float g = Wt.g[i];
      m01.x = fmaf(g, r01[sl].x, m01.x);
      m01.y = fmaf(g, r01[sl].y, m01.y);
      m23.x = fmaf(g, r23[sl].x, m23.x);
      m23.y = fmaf(g, r23[sl].y, m23.y);
      m4 = fmaf(g, r4[sl], m4);
    }
    float mux = m01.x, muy = m01.y, bxx = m23.x, byy = m23.y, bxy = m4;
    float mux2 = mux * mux, muy2 = muy * muy, muxy = mux * muy;
    float sx = bxx - mux2, sy = byy - muy2, sxy = bxy - muxy;
    float num = fmaf(2.f, muxy, C1f) * fmaf(2.f, sxy, C2f);
    float den = (mux2 + muy2 + C1f) * (sx + sy + C2f);
    fsum += 1.f - num * __builtin_amdgcn_rcpf(den);
  }
  lsum += (double)fsum;
}

// D-blur + SSIM + mean-reduce. grid = (h=S, n, dchunk=4); block = 192 (w).
// Register ring of 11 planes, ping-pong staging one 11-batch ahead.
__global__ __launch_bounds__(192) void k_blurD_ssim(
    const uint2* __restrict__ p0123, const __half* __restrict__ p4,
    double* __restrict__ acc, GaussW Wt) {
  const int w = threadIdx.x;
  const int h = blockIdx.x;
  const long long n = blockIdx.y;
  const int d0 = (int)blockIdx.z * DCH;
  const long long base = n * S3 + (long long)h * S + w;
  const uint2* q0123 = p0123 + base;
  const __half* q4 = p4 + base;

  float2 r01[K], r23[K];
  float r4[K];
  // preload counters 0..9 -> slots 0..9 (planes d0-5..d0+4, guard low)
#pragma unroll
  for (int c = 0; c < K - 1; ++c) {
    int d = d0 - R + c;
    if ((unsigned)d < (unsigned)S) {
      long long o = (long long)d * S2;
      uint2 v = q0123[o];
      r01[c] = __half22float2(__builtin_bit_cast(__half2, v.x));
      r23[c] = __half22float2(__builtin_bit_cast(__half2, v.y));
      r4[c] = __half2float(q4[o]);
    } else {
      r01[c] = make_float2(0.f, 0.f);
      r23[c] = make_float2(0.f, 0.f);
      r4[c] = 0.f;
    }
  }
  r01[K - 1] = make_float2(0.f, 0.f);
  r23[K - 1] = make_float2(0.f, 0.f);
  r4[K - 1] = 0.f;

  uint2 sab0[K], sab1[K];
  __half se0[K], se1[K];
  double lsum = 0.0;

  // plane ranges: d0+5..15, d0+16..26, d0+27..37 (max 181: safe);
  // d0+38..48 and d0+49..52 guarded (max 196).
  stageB<K, false>(q0123, q4, d0 + 5, sab0, se0);   // counters 10..20
  stageB<K, false>(q0123, q4, d0 + 16, sab1, se1);  // counters 21..31
  consumeB<K>(sab0, se0, Wt, r01, r23, r4, lsum);   // t = 0..10
  stageB<K, false>(q0123, q4, d0 + 27, sab0, se0);  // counters 32..42
  consumeB<K>(sab1, se1, Wt, r01, r23, r4, lsum);   // t = 11..21
  stageB<K, true>(q0123, q4, d0 + 38, sab1, se1);   // counters 43..53
  consumeB<K>(sab0, se0, Wt, r01, r23, r4, lsum);   // t = 22..32
  stageB<4, true>(q0123, q4, d0 + 49, sab0, se0);   // counters 54..57
  consumeB<K>(sab1, se1, Wt, r01, r23, r4, lsum);   // t = 33..43
  consumeB<4>(sab0, se0, Wt, r01, r23, r4, lsum);   // t = 44..47

  // block reduction: wave shuffle -> LDS -> one atomic per block
  double v = lsum;
#pragma unroll
  for (int o = 32; o > 0; o >>= 1) v += __shfl_down(v, o, 64);
  __shared__ double wsum[3];
  int lane = threadIdx.x & 63, wv = threadIdx.x >> 6;
  if (lane == 0) wsum[wv] = v;
  __syncthreads();
  if (threadIdx.x == 0) atomicAdd(acc, wsum[0] + wsum[1] + wsum[2]);
}

}  // namespace

extern "C" void kernel_launch(void* const* d_in, const int* in_sizes, int n_in,
                              void* d_out, int out_size, void* d_ws, size_t ws_size,
                              hipStream_t stream) {
  (void)in_sizes; (void)n_in; (void)out_size;
  const float* gt = (const float*)d_in[0];
  const float* pr = (const float*)d_in[1];
  float* out = (float*)d_out;
  double* acc = (double*)d_ws;

  GaussW W;
  {
    double gg[K], sum = 0.0;
    for (int i = 0; i < K; ++i) {
      double x = (double)(i - K / 2);
      gg[i] = exp(-(x * x) / (2.0 * 1.5 * 1.5)) / (sqrt(2.0 * M_PI) * 1.5);
      sum += gg[i];
    }
    for (int i = 0; i < K; ++i) W.g[i] = (float)(gg[i] / sum);
  }

  auto run = [&](long long base_n, int nb) {
    size_t vox = (size_t)nb * S3;
    uint2* p0123 = (uint2*)((char*)d_ws + 256);
    __half* p4 = (__half*)(p0123 + vox);
    k_blurWH<<<dim3(S, S / HCH, nb), dim3(192), 0, stream>>>(
        gt, pr, p0123, p4, base_n * S3, W);
    k_blurD_ssim<<<dim3(S, nb, S / DCH), dim3(192), 0, stream>>>(
        p0123, p4, acc, W);
  };
  auto need = [](int nb) { return (size_t)256 + (size_t)nb * S3 * 10; };  // 8+2 B/voxel

  k_init<<<dim3(1), dim3(1), 0, stream>>>(acc);
  // R8: run in nb=2 chunks even when ws fits nb=4. Per-chunk intermediate =
  // 141 MB < 256 MB Infinity Cache, so B's plane-strided reads (and A's
  // writes) stay in L3 instead of round-tripping to HBM. The intermediate
  // is 566 MB of the pipeline's 792 MB total traffic — the dominant term.
  if (ws_size >= need(2)) {
    run(0, 2);
    run(2, 2);
  } else {
    for (int g = 0; g < NB; ++g) run(g, 1);
  }
  k_final<<<dim3(1), dim3(1), 0, stream>>>(acc, out);
}